// Round 1
// baseline (5228.403 us; speedup 1.0000x reference)
//
#include <hip/hip_runtime.h>

#define B 4
#define C 512
#define HW 4096
#define NG 32
#define GSZ 65536   // (C/NG)*HW = 16*4096
#define TI 16
#define LQK 520     // padded row stride (ushorts) for q/k tiles
#define LV 24       // padded row stride (ushorts) for v tile

typedef unsigned short u16;
typedef unsigned int u32;

__device__ __forceinline__ float bf2f(u16 u) {
    union { u32 i; float f; } x; x.i = ((u32)u) << 16; return x.f;
}
__device__ __forceinline__ u16 f2bf(float f) {
    union { u32 i; float f; } x; x.f = f;
    u32 r = x.i + 0x7FFF + ((x.i >> 16) & 1);   // round-nearest-even
    return (u16)(r >> 16);
}

// ---------------- Kernel 1: GroupNorm -> bf16 xn ----------------
__global__ __launch_bounds__(256) void gn_kernel(
        const float* __restrict__ x, const float* __restrict__ gamma,
        const float* __restrict__ beta, u16* __restrict__ xn) {
    const int gl = blockIdx.x;                // b*32 + g
    const size_t base = (size_t)gl * GSZ;
    const int tid = threadIdx.x;
    float s = 0.f, s2 = 0.f;
    for (int i = tid * 4; i < GSZ; i += 1024) {
        float4 v4 = *(const float4*)(x + base + i);
        s  += v4.x + v4.y + v4.z + v4.w;
        s2 += v4.x*v4.x + v4.y*v4.y + v4.z*v4.z + v4.w*v4.w;
    }
    #pragma unroll
    for (int off = 32; off > 0; off >>= 1) {
        s  += __shfl_down(s, off, 64);
        s2 += __shfl_down(s2, off, 64);
    }
    __shared__ float rs[4], rs2[4], bc[2];
    int lane = tid & 63, wid = tid >> 6;
    if (lane == 0) { rs[wid] = s; rs2[wid] = s2; }
    __syncthreads();
    if (tid == 0) {
        float ts  = rs[0] + rs[1] + rs[2] + rs[3];
        float ts2 = rs2[0] + rs2[1] + rs2[2] + rs2[3];
        float mean = ts * (1.f / GSZ);
        float var  = ts2 * (1.f / GSZ) - mean * mean;
        bc[0] = mean; bc[1] = rsqrtf(var + 1e-6f);
    }
    __syncthreads();
    const float mean = bc[0], rstd = bc[1];
    const int cbase = (gl & (NG - 1)) * (C / NG);
    for (int i = tid * 4; i < GSZ; i += 1024) {
        int ch = cbase + (i >> 12);
        float g = gamma[ch], bb = beta[ch];
        float4 v4 = *(const float4*)(x + base + i);
        ushort4 r4;
        r4.x = f2bf((v4.x - mean) * rstd * g + bb);
        r4.y = f2bf((v4.y - mean) * rstd * g + bb);
        r4.z = f2bf((v4.z - mean) * rstd * g + bb);
        r4.w = f2bf((v4.w - mean) * rstd * g + bb);
        *(ushort4*)(xn + base + i) = r4;
    }
}

// ---------------- Kernel 2: fused QKV projection ----------------
// q[b,o,i] = bq[o] + sum_c wq[o,c]*xn[b,c,i]; writes qT/kT as (b,hw,c), v as (b,c,hw)
__global__ __launch_bounds__(256) void qkv_kernel(
        const u16* __restrict__ xn,
        const float* __restrict__ wq, const float* __restrict__ bq,
        const float* __restrict__ wk, const float* __restrict__ bk,
        const float* __restrict__ wv, const float* __restrict__ bv,
        u16* __restrict__ qT, u16* __restrict__ kT, u16* __restrict__ v) {
    const int b = blockIdx.z, o0 = blockIdx.y * 64, i0 = blockIdx.x * 64;
    const int tid = threadIdx.x;
    const int tx = tid & 15, ty = tid >> 4;
    __shared__ float wS[3][16][65];
    __shared__ float xS[16][65];
    const float* wptr[3] = { wq, wk, wv };
    float acc[3][4][4];
    #pragma unroll
    for (int a = 0; a < 4; a++) {
        float b0 = bq[o0 + ty*4 + a], b1 = bk[o0 + ty*4 + a], b2 = bv[o0 + ty*4 + a];
        #pragma unroll
        for (int bb = 0; bb < 4; bb++) { acc[0][a][bb] = b0; acc[1][a][bb] = b1; acc[2][a][bb] = b2; }
    }
    for (int c0 = 0; c0 < C; c0 += 16) {
        __syncthreads();
        {
            int row = tid >> 2, col = (tid & 3) * 4;
            #pragma unroll
            for (int m = 0; m < 3; m++) {
                float4 w4 = *(const float4*)(wptr[m] + (size_t)(o0 + row) * C + c0 + col);
                wS[m][col+0][row] = w4.x; wS[m][col+1][row] = w4.y;
                wS[m][col+2][row] = w4.z; wS[m][col+3][row] = w4.w;
            }
            int r = tid >> 4, ii = (tid & 15) * 4;
            ushort4 u4 = *(const ushort4*)(xn + ((size_t)b*C + c0 + r) * HW + i0 + ii);
            xS[r][ii+0] = bf2f(u4.x); xS[r][ii+1] = bf2f(u4.y);
            xS[r][ii+2] = bf2f(u4.z); xS[r][ii+3] = bf2f(u4.w);
        }
        __syncthreads();
        #pragma unroll
        for (int kk = 0; kk < 16; kk++) {
            float xv[4], wv_[3][4];
            #pragma unroll
            for (int bb = 0; bb < 4; bb++) xv[bb] = xS[kk][tx*4 + bb];
            #pragma unroll
            for (int m = 0; m < 3; m++)
                #pragma unroll
                for (int a = 0; a < 4; a++) wv_[m][a] = wS[m][kk][ty*4 + a];
            #pragma unroll
            for (int m = 0; m < 3; m++)
                #pragma unroll
                for (int a = 0; a < 4; a++)
                    #pragma unroll
                    for (int bb = 0; bb < 4; bb++)
                        acc[m][a][bb] += wv_[m][a] * xv[bb];
        }
    }
    #pragma unroll
    for (int a = 0; a < 4; a++) {
        int o = o0 + ty*4 + a;
        #pragma unroll
        for (int bb = 0; bb < 4; bb++) {
            int i = i0 + tx*4 + bb;
            qT[((size_t)b*HW + i)*C + o] = f2bf(acc[0][a][bb]);
            kT[((size_t)b*HW + i)*C + o] = f2bf(acc[1][a][bb]);
            v [((size_t)b*C  + o)*HW + i] = f2bf(acc[2][a][bb]);
        }
    }
}

// ---------------- Kernel 3: streaming attention (online softmax) ----------------
__global__ __launch_bounds__(256) void attn_kernel(
        const u16* __restrict__ qT, const u16* __restrict__ kT,
        const u16* __restrict__ v, u16* __restrict__ oT) {
    const int b = blockIdx.y;
    const int i0 = blockIdx.x * TI;
    const int tid = threadIdx.x;
    __shared__ __align__(16) u16 qs[TI][LQK];
    __shared__ __align__(16) u16 ks[TI][LQK];
    __shared__ __align__(16) u16 vs[C][LV];
    __shared__ __align__(16) float Sb[TI][20];
    __shared__ __align__(16) float Pb[TI][20];
    __shared__ float mrow[TI], lrow[TI], arow[TI];

    #pragma unroll
    for (int rep = 0; rep < 4; rep++) {
        int ci = tid + 256 * rep;           // 0..1023
        int r = ci >> 6, cc = (ci & 63) * 8;
        uint4 u = *(const uint4*)(qT + ((size_t)b*HW + i0 + r)*C + cc);
        *(uint4*)&qs[r][cc] = u;
    }
    if (tid < TI) { mrow[tid] = -1e30f; lrow[tid] = 0.f; }
    float o_acc[2][TI];
    #pragma unroll
    for (int cc = 0; cc < 2; cc++)
        #pragma unroll
        for (int i = 0; i < TI; i++) o_acc[cc][i] = 0.f;

    const int si = tid >> 4, sj = tid & 15;

    #pragma unroll 1
    for (int j0 = 0; j0 < HW; j0 += TI) {
        __syncthreads();
        #pragma unroll
        for (int rep = 0; rep < 4; rep++) {
            int ci = tid + 256 * rep;
            int r = ci >> 6, cc = (ci & 63) * 8;
            uint4 u = *(const uint4*)(kT + ((size_t)b*HW + j0 + r)*C + cc);
            *(uint4*)&ks[r][cc] = u;
        }
        #pragma unroll
        for (int rep = 0; rep < 4; rep++) {
            int ci = tid + 256 * rep;       // 0..1023
            int c = ci >> 1, jj = (ci & 1) * 8;
            uint4 u = *(const uint4*)(v + ((size_t)b*C + c)*HW + j0 + jj);
            *(uint4*)&vs[c][jj] = u;
        }
        __syncthreads();
        // ---- S = q^T k (each thread one (i,j) pair) ----
        {
            const u16* qp = &qs[si][0];
            const u16* kp = &ks[sj][0];
            float s = 0.f;
            #pragma unroll 4
            for (int c = 0; c < C; c += 8) {
                uint4 qu = *(const uint4*)(qp + c);
                uint4 ku = *(const uint4*)(kp + c);
                s += bf2f((u16)qu.x)*bf2f((u16)ku.x) + bf2f((u16)(qu.x>>16))*bf2f((u16)(ku.x>>16));
                s += bf2f((u16)qu.y)*bf2f((u16)ku.y) + bf2f((u16)(qu.y>>16))*bf2f((u16)(ku.y>>16));
                s += bf2f((u16)qu.z)*bf2f((u16)ku.z) + bf2f((u16)(qu.z>>16))*bf2f((u16)(ku.z>>16));
                s += bf2f((u16)qu.w)*bf2f((u16)ku.w) + bf2f((u16)(qu.w>>16))*bf2f((u16)(ku.w>>16));
            }
            Sb[si][sj] = s * 0.04419417382415922f;   // * 512^-0.5
        }
        __syncthreads();
        // ---- online softmax update (one thread per row) ----
        if (tid < TI) {
            int i = tid;
            float m_old = mrow[i], mx = m_old;
            #pragma unroll
            for (int j = 0; j < TI; j++) mx = fmaxf(mx, Sb[i][j]);
            float alpha = __expf(m_old - mx);
            float sum = 0.f;
            #pragma unroll
            for (int j = 0; j < TI; j++) {
                float p = __expf(Sb[i][j] - mx);
                Pb[i][j] = p; sum += p;
            }
            lrow[i] = lrow[i] * alpha + sum;
            mrow[i] = mx;
            arow[i] = alpha;
        }
        __syncthreads();
        // ---- O += P * v (thread owns channels c = tid, tid+256) ----
        {
            float vf[2][TI];
            #pragma unroll
            for (int cc = 0; cc < 2; cc++) {
                const u16* vp = &vs[tid + 256*cc][0];
                uint4 u0 = *(const uint4*)(vp);
                uint4 u1 = *(const uint4*)(vp + 8);
                vf[cc][0]=bf2f((u16)u0.x);  vf[cc][1]=bf2f((u16)(u0.x>>16));
                vf[cc][2]=bf2f((u16)u0.y);  vf[cc][3]=bf2f((u16)(u0.y>>16));
                vf[cc][4]=bf2f((u16)u0.z);  vf[cc][5]=bf2f((u16)(u0.z>>16));
                vf[cc][6]=bf2f((u16)u0.w);  vf[cc][7]=bf2f((u16)(u0.w>>16));
                vf[cc][8]=bf2f((u16)u1.x);  vf[cc][9]=bf2f((u16)(u1.x>>16));
                vf[cc][10]=bf2f((u16)u1.y); vf[cc][11]=bf2f((u16)(u1.y>>16));
                vf[cc][12]=bf2f((u16)u1.z); vf[cc][13]=bf2f((u16)(u1.z>>16));
                vf[cc][14]=bf2f((u16)u1.w); vf[cc][15]=bf2f((u16)(u1.w>>16));
            }
            #pragma unroll
            for (int i = 0; i < TI; i++) {
                float al = arow[i];
                float4 t0 = *(const float4*)&Pb[i][0];
                float4 t1 = *(const float4*)&Pb[i][4];
                float4 t2 = *(const float4*)&Pb[i][8];
                float4 t3 = *(const float4*)&Pb[i][12];
                float p[16] = { t0.x,t0.y,t0.z,t0.w, t1.x,t1.y,t1.z,t1.w,
                                t2.x,t2.y,t2.z,t2.w, t3.x,t3.y,t3.z,t3.w };
                #pragma unroll
                for (int cc = 0; cc < 2; cc++) {
                    float o = o_acc[cc][i] * al;
                    #pragma unroll
                    for (int j = 0; j < TI; j++) o += p[j] * vf[cc][j];
                    o_acc[cc][i] = o;
                }
            }
        }
    }
    __syncthreads();
    #pragma unroll
    for (int i = 0; i < TI; i++) {
        float inv = 1.f / lrow[i];
        size_t rowoff = ((size_t)b*HW + i0 + i) * C;
        oT[rowoff + tid]       = f2bf(o_acc[0][i] * inv);
        oT[rowoff + tid + 256] = f2bf(o_acc[1][i] * inv);
    }
}

// ---------------- Kernel 4: output projection + bias + residual ----------------
__global__ __launch_bounds__(256) void proj_kernel(
        const u16* __restrict__ oT, const float* __restrict__ wo,
        const float* __restrict__ bo, const float* __restrict__ x,
        float* __restrict__ out) {
    const int b = blockIdx.z, o0 = blockIdx.y * 64, i0 = blockIdx.x * 64;
    const int tid = threadIdx.x;
    const int tx = tid & 15, ty = tid >> 4;
    __shared__ float wS[16][65];
    __shared__ float oS[16][65];
    float acc[4][4];
    #pragma unroll
    for (int a = 0; a < 4; a++)
        #pragma unroll
        for (int bb = 0; bb < 4; bb++) acc[a][bb] = 0.f;
    for (int c0 = 0; c0 < C; c0 += 16) {
        __syncthreads();
        {
            int row = tid >> 2, col = (tid & 3) * 4;
            float4 w4 = *(const float4*)(wo + (size_t)(o0 + row) * C + c0 + col);
            wS[col+0][row] = w4.x; wS[col+1][row] = w4.y;
            wS[col+2][row] = w4.z; wS[col+3][row] = w4.w;
            // oT tile: (i rows) x (16 c), contiguous along c
            int r = tid >> 2, cc = (tid & 3) * 4;
            ushort4 u4 = *(const ushort4*)(oT + ((size_t)b*HW + i0 + r)*C + c0 + cc);
            oS[cc+0][r] = bf2f(u4.x); oS[cc+1][r] = bf2f(u4.y);
            oS[cc+2][r] = bf2f(u4.z); oS[cc+3][r] = bf2f(u4.w);
        }
        __syncthreads();
        #pragma unroll
        for (int kk = 0; kk < 16; kk++) {
            float ov[4], wv_[4];
            #pragma unroll
            for (int bb = 0; bb < 4; bb++) ov[bb] = oS[kk][tx*4 + bb];
            #pragma unroll
            for (int a = 0; a < 4; a++) wv_[a] = wS[kk][ty*4 + a];
            #pragma unroll
            for (int a = 0; a < 4; a++)
                #pragma unroll
                for (int bb = 0; bb < 4; bb++)
                    acc[a][bb] += wv_[a] * ov[bb];
        }
    }
    #pragma unroll
    for (int a = 0; a < 4; a++) {
        int o = o0 + ty*4 + a;
        float bias = bo[o];
        size_t idx = ((size_t)b*C + o)*HW + i0 + tx*4;
        float4 xr = *(const float4*)(x + idx);
        float4 r;
        r.x = acc[a][0] + bias + xr.x;
        r.y = acc[a][1] + bias + xr.y;
        r.z = acc[a][2] + bias + xr.z;
        r.w = acc[a][3] + bias + xr.w;
        *(float4*)(out + idx) = r;
    }
}

extern "C" void kernel_launch(void* const* d_in, const int* in_sizes, int n_in,
                              void* d_out, int out_size, void* d_ws, size_t ws_size,
                              hipStream_t stream) {
    const float* x    = (const float*)d_in[0];
    const float* gn_w = (const float*)d_in[1];
    const float* gn_b = (const float*)d_in[2];
    const float* wq   = (const float*)d_in[3];
    const float* bq   = (const float*)d_in[4];
    const float* wk   = (const float*)d_in[5];
    const float* bk   = (const float*)d_in[6];
    const float* wv   = (const float*)d_in[7];
    const float* bv   = (const float*)d_in[8];
    const float* wo   = (const float*)d_in[9];
    const float* bo   = (const float*)d_in[10];
    float* out = (float*)d_out;

    const size_t S1 = (size_t)B * C * HW;   // 8388608 elements
    u16* xn = (u16*)d_ws;
    u16* qT = xn + S1;
    u16* kT = qT + S1;
    u16* v  = kT + S1;
    u16* oT = v  + S1;

    hipLaunchKernelGGL(gn_kernel,  dim3(B*NG), dim3(256), 0, stream, x, gn_w, gn_b, xn);
    hipLaunchKernelGGL(qkv_kernel, dim3(HW/64, C/64, B), dim3(256), 0, stream,
                       xn, wq, bq, wk, bk, wv, bv, qT, kT, v);
    hipLaunchKernelGGL(attn_kernel, dim3(HW/TI, B), dim3(256), 0, stream, qT, kT, v, oT);
    hipLaunchKernelGGL(proj_kernel, dim3(HW/64, C/64, B), dim3(256), 0, stream, oT, wo, bo, x, out);
}

// Round 2
// 1069.492 us; speedup vs baseline: 4.8887x; 4.8887x over previous
//
#include <hip/hip_runtime.h>

#define B 4
#define C 512
#define HW 4096
#define NG 32
#define GSZ 65536   // (C/NG)*HW = 16*4096

typedef unsigned short u16;
typedef unsigned int u32;
typedef __attribute__((ext_vector_type(8))) short short8;
typedef __attribute__((ext_vector_type(4))) float f32x4;

__device__ __forceinline__ float bf2f(u16 u) {
    union { u32 i; float f; } x; x.i = ((u32)u) << 16; return x.f;
}
__device__ __forceinline__ u16 f2bf(float f) {
    union { u32 i; float f; } x; x.f = f;
    u32 r = x.i + 0x7FFF + ((x.i >> 16) & 1);   // round-nearest-even
    return (u16)(r >> 16);
}

// async global->LDS, 16B per lane. LDS dest = wave-uniform base + lane*16.
__device__ __forceinline__ void gld16(const u16* g, u16* l) {
    __builtin_amdgcn_global_load_lds(
        (const __attribute__((address_space(1))) void*)g,
        (__attribute__((address_space(3))) void*)l, 16, 0, 0);
}

// ---------------- Kernel 1: GroupNorm -> bf16 xn ----------------
__global__ __launch_bounds__(256) void gn_kernel(
        const float* __restrict__ x, const float* __restrict__ gamma,
        const float* __restrict__ beta, u16* __restrict__ xn) {
    const int gl = blockIdx.x;                // b*32 + g
    const size_t base = (size_t)gl * GSZ;
    const int tid = threadIdx.x;
    float s = 0.f, s2 = 0.f;
    for (int i = tid * 4; i < GSZ; i += 1024) {
        float4 v4 = *(const float4*)(x + base + i);
        s  += v4.x + v4.y + v4.z + v4.w;
        s2 += v4.x*v4.x + v4.y*v4.y + v4.z*v4.z + v4.w*v4.w;
    }
    #pragma unroll
    for (int off = 32; off > 0; off >>= 1) {
        s  += __shfl_down(s, off, 64);
        s2 += __shfl_down(s2, off, 64);
    }
    __shared__ float rs[4], rs2[4], bc[2];
    int lane = tid & 63, wid = tid >> 6;
    if (lane == 0) { rs[wid] = s; rs2[wid] = s2; }
    __syncthreads();
    if (tid == 0) {
        float ts  = rs[0] + rs[1] + rs[2] + rs[3];
        float ts2 = rs2[0] + rs2[1] + rs2[2] + rs2[3];
        float mean = ts * (1.f / GSZ);
        float var  = ts2 * (1.f / GSZ) - mean * mean;
        bc[0] = mean; bc[1] = rsqrtf(var + 1e-6f);
    }
    __syncthreads();
    const float mean = bc[0], rstd = bc[1];
    const int cbase = (gl & (NG - 1)) * (C / NG);
    for (int i = tid * 4; i < GSZ; i += 1024) {
        int ch = cbase + (i >> 12);
        float g = gamma[ch], bb = beta[ch];
        float4 v4 = *(const float4*)(x + base + i);
        ushort4 r4;
        r4.x = f2bf((v4.x - mean) * rstd * g + bb);
        r4.y = f2bf((v4.y - mean) * rstd * g + bb);
        r4.z = f2bf((v4.z - mean) * rstd * g + bb);
        r4.w = f2bf((v4.w - mean) * rstd * g + bb);
        *(ushort4*)(xn + base + i) = r4;
    }
}

// ---------------- Kernel 2: fused QKV projection ----------------
// writes qT/kT as (b,hw,c); V as swizzled LDS-image chunks:
//   chunk ch = i>>5, j = i&31; u16 idx = ((b*128+ch)*16384) + c*32 + ((j>>3)^((c>>2)&3))*8 + (j&7)
__global__ __launch_bounds__(256) void qkv_kernel(
        const u16* __restrict__ xn,
        const float* __restrict__ wq, const float* __restrict__ bq,
        const float* __restrict__ wk, const float* __restrict__ bk,
        const float* __restrict__ wv, const float* __restrict__ bv,
        u16* __restrict__ qT, u16* __restrict__ kT, u16* __restrict__ vimg) {
    const int b = blockIdx.z, o0 = blockIdx.y * 64, i0 = blockIdx.x * 64;
    const int tid = threadIdx.x;
    const int tx = tid & 15, ty = tid >> 4;
    __shared__ float wS[3][16][65];
    __shared__ float xS[16][65];
    const float* wptr[3] = { wq, wk, wv };
    float acc[3][4][4];
    #pragma unroll
    for (int a = 0; a < 4; a++) {
        float b0 = bq[o0 + ty*4 + a], b1 = bk[o0 + ty*4 + a], b2 = bv[o0 + ty*4 + a];
        #pragma unroll
        for (int bb = 0; bb < 4; bb++) { acc[0][a][bb] = b0; acc[1][a][bb] = b1; acc[2][a][bb] = b2; }
    }
    for (int c0 = 0; c0 < C; c0 += 16) {
        __syncthreads();
        {
            int row = tid >> 2, col = (tid & 3) * 4;
            #pragma unroll
            for (int m = 0; m < 3; m++) {
                float4 w4 = *(const float4*)(wptr[m] + (size_t)(o0 + row) * C + c0 + col);
                wS[m][col+0][row] = w4.x; wS[m][col+1][row] = w4.y;
                wS[m][col+2][row] = w4.z; wS[m][col+3][row] = w4.w;
            }
            int r = tid >> 4, ii = (tid & 15) * 4;
            ushort4 u4 = *(const ushort4*)(xn + ((size_t)b*C + c0 + r) * HW + i0 + ii);
            xS[r][ii+0] = bf2f(u4.x); xS[r][ii+1] = bf2f(u4.y);
            xS[r][ii+2] = bf2f(u4.z); xS[r][ii+3] = bf2f(u4.w);
        }
        __syncthreads();
        #pragma unroll
        for (int kk = 0; kk < 16; kk++) {
            float xv[4], wv_[3][4];
            #pragma unroll
            for (int bb = 0; bb < 4; bb++) xv[bb] = xS[kk][tx*4 + bb];
            #pragma unroll
            for (int m = 0; m < 3; m++)
                #pragma unroll
                for (int a = 0; a < 4; a++) wv_[m][a] = wS[m][kk][ty*4 + a];
            #pragma unroll
            for (int m = 0; m < 3; m++)
                #pragma unroll
                for (int a = 0; a < 4; a++)
                    #pragma unroll
                    for (int bb = 0; bb < 4; bb++)
                        acc[m][a][bb] += wv_[m][a] * xv[bb];
        }
    }
    #pragma unroll
    for (int a = 0; a < 4; a++) {
        int o = o0 + ty*4 + a;
        #pragma unroll
        for (int bb = 0; bb < 4; bb++) {
            int i = i0 + tx*4 + bb;
            qT[((size_t)b*HW + i)*C + o] = f2bf(acc[0][a][bb]);
            kT[((size_t)b*HW + i)*C + o] = f2bf(acc[1][a][bb]);
            int ch = i >> 5, j = i & 31;
            vimg[((size_t)b*128 + ch)*16384 + (size_t)o*32 +
                 (((j>>3) ^ ((o>>2)&3)) << 3) + (j & 7)] = f2bf(acc[2][a][bb]);
        }
    }
}

// ---------------- Kernel 3: MFMA flash attention ----------------
// Block: 64 q-rows, 4 waves. Wave w: S rows [16w,16w+16); PV cols c in [128w,128w+128).
__global__ __launch_bounds__(256) void attn_kernel(
        const u16* __restrict__ qT, const u16* __restrict__ kT,
        const u16* __restrict__ vimg, u16* __restrict__ oT) {
    const int b = blockIdx.y;
    const int i0 = blockIdx.x * 64;
    const int tid = threadIdx.x;
    const int w = tid >> 6;
    const int lane = tid & 63;
    const int q = lane >> 4;
    const int n = lane & 15;

    __shared__ __align__(16) u16 kbuf[2][32*520];   // 66,560 B (row stride 1040B: 2-way free)
    __shared__ __align__(16) u16 vbuf[2][16384];    // 65,536 B (XOR-swizzled image)
    __shared__ __align__(16) u16 pbuf[64*40];       //  5,120 B (row stride 80B: 2-way free)
    __shared__ __align__(16) float alphabuf[64];
    __shared__ __align__(16) float lbuf[64];
    __shared__ int flagbuf[4];

    // persistent Q A-fragments: rows i0+16w+n, k = kstep*32 + q*8 .. +7
    short8 qf[16];
    {
        const u16* qrow = qT + ((size_t)b*HW + i0 + w*16 + n) * C + q*8;
        #pragma unroll
        for (int k = 0; k < 16; k++) {
            uint4 u = *(const uint4*)(qrow + k*32);
            qf[k] = *(const short8*)&u;
        }
    }
    f32x4 oacc[4][8];
    #pragma unroll
    for (int mt = 0; mt < 4; mt++)
        #pragma unroll
        for (int nt = 0; nt < 8; nt++)
            oacc[mt][nt] = (f32x4){0.f, 0.f, 0.f, 0.f};
    float mstate[4] = {-1e30f, -1e30f, -1e30f, -1e30f};
    float lsum[4]   = {0.f, 0.f, 0.f, 0.f};

    const u16* kTb = kT + (size_t)b*HW*C;
    const u16* vTb = vimg + (size_t)b*128*16384;

    // prologue: stage chunk 0 into buffer 0
    {
        #pragma unroll
        for (int ii = 0; ii < 8; ii++) {
            int row = w*8 + ii;
            gld16(kTb + (size_t)row*C + lane*8, &kbuf[0][row*520]);
        }
        #pragma unroll
        for (int ii = 0; ii < 8; ii++) {
            int t = w*8 + ii;
            gld16(vTb + t*512 + lane*8, &vbuf[0][t*512]);
        }
    }
    const float scale = 0.04419417382415922f;   // 512^-0.5

    for (int t = 0; t < 128; ++t) {
        const int cur = t & 1;
        __syncthreads();   // A: K/V(cur) ready, prev compute done
        if (t + 1 < 128) {  // prefetch K(t+1) -> overlaps S phase
            const u16* gk = kTb + (size_t)(t+1)*32*C;
            #pragma unroll
            for (int ii = 0; ii < 8; ii++) {
                int row = w*8 + ii;
                gld16(gk + (size_t)row*C + lane*8, &kbuf[cur^1][row*520]);
            }
        }
        // ---- S = Q K^T ----
        f32x4 s0 = {0.f,0.f,0.f,0.f}, s1 = {0.f,0.f,0.f,0.f};
        const u16* kb = kbuf[cur];
        const u16* kb0 = kb + n*520 + q*8;
        const u16* kb1 = kb + (16+n)*520 + q*8;
        #pragma unroll
        for (int k = 0; k < 16; k++) {
            short8 bf = *(const short8*)(kb0 + k*32);
            s0 = __builtin_amdgcn_mfma_f32_16x16x32_bf16(qf[k], bf, s0, 0, 0, 0);
        }
        #pragma unroll
        for (int k = 0; k < 16; k++) {
            short8 bf = *(const short8*)(kb1 + k*32);
            s1 = __builtin_amdgcn_mfma_f32_16x16x32_bf16(qf[k], bf, s1, 0, 0, 0);
        }
        // ---- online softmax (rows q*4+r of wave-w block) ----
        float alr[4];
        #pragma unroll
        for (int r = 0; r < 4; r++) {
            float v0 = s0[r]*scale, v1 = s1[r]*scale;
            float mx = fmaxf(v0, v1);
            mx = fmaxf(mx, __shfl_xor(mx, 1));
            mx = fmaxf(mx, __shfl_xor(mx, 2));
            mx = fmaxf(mx, __shfl_xor(mx, 4));
            mx = fmaxf(mx, __shfl_xor(mx, 8));
            float mnew = fmaxf(mstate[r], mx);
            float al = __expf(mstate[r] - mnew);
            float p0 = __expf(v0 - mnew);
            float p1 = __expf(v1 - mnew);
            mstate[r] = mnew;
            lsum[r] = lsum[r]*al + (p0 + p1);
            alr[r] = al;
            pbuf[(w*16 + q*4 + r)*40 + n]      = f2bf(p0);
            pbuf[(w*16 + q*4 + r)*40 + 16 + n] = f2bf(p1);
        }
        int chg = (alr[0]!=1.f) | (alr[1]!=1.f) | (alr[2]!=1.f) | (alr[3]!=1.f);
        int anyc = __any(chg);
        if (lane == 0) flagbuf[w] = anyc;
        if (n == 0) {
            #pragma unroll
            for (int r = 0; r < 4; r++) alphabuf[w*16 + q*4 + r] = alr[r];
        }
        __syncthreads();   // B: P/alpha/flags visible; V(cur) ready
        if (t + 1 < 128) {  // prefetch V(t+1) -> overlaps PV phase
            const u16* gv = vTb + (size_t)(t+1)*16384;
            #pragma unroll
            for (int ii = 0; ii < 8; ii++) {
                int tt = w*8 + ii;
                gld16(gv + tt*512 + lane*8, &vbuf[cur^1][tt*512]);
            }
        }
        // ---- rescale O by alpha (skip when no row max changed: alpha==1 exactly) ----
        int doR = flagbuf[0] | flagbuf[1] | flagbuf[2] | flagbuf[3];
        if (doR) {
            #pragma unroll
            for (int mt = 0; mt < 4; mt++) {
                f32x4 a4 = *(const f32x4*)&alphabuf[mt*16 + q*4];
                #pragma unroll
                for (int nt = 0; nt < 8; nt++) {
                    oacc[mt][nt][0] *= a4[0];
                    oacc[mt][nt][1] *= a4[1];
                    oacc[mt][nt][2] *= a4[2];
                    oacc[mt][nt][3] *= a4[3];
                }
            }
        }
        // ---- O += P V  (wave w: cols 128w..128w+127, all 64 rows) ----
        short8 pf[4];
        #pragma unroll
        for (int mt = 0; mt < 4; mt++)
            pf[mt] = *(const short8*)&pbuf[(mt*16 + n)*40 + q*8];
        const u16* vb = vbuf[cur];
        #pragma unroll
        for (int nt = 0; nt < 8; nt++) {
            int c = w*128 + nt*16 + n;
            short8 vf = *(const short8*)&vb[c*32 + ((q ^ ((c>>2)&3)) << 3)];
            #pragma unroll
            for (int mt = 0; mt < 4; mt++)
                oacc[mt][nt] = __builtin_amdgcn_mfma_f32_16x16x32_bf16(pf[mt], vf, oacc[mt][nt], 0, 0, 0);
        }
    }
    // ---- epilogue: final l per row -> LDS, then scaled store ----
    #pragma unroll
    for (int r = 0; r < 4; r++) {
        float l = lsum[r];
        l += __shfl_xor(l, 1);
        l += __shfl_xor(l, 2);
        l += __shfl_xor(l, 4);
        l += __shfl_xor(l, 8);
        if (n == 0) lbuf[w*16 + q*4 + r] = l;
    }
    __syncthreads();
    #pragma unroll
    for (int mt = 0; mt < 4; mt++) {
        f32x4 l4 = *(const f32x4*)&lbuf[mt*16 + q*4];
        float i0r = 1.f / l4[0], i1r = 1.f / l4[1], i2r = 1.f / l4[2], i3r = 1.f / l4[3];
        #pragma unroll
        for (int nt = 0; nt < 8; nt++) {
            int cc = w*128 + nt*16 + n;
            size_t base = ((size_t)b*HW + i0 + mt*16 + q*4) * C + cc;
            oT[base        ] = f2bf(oacc[mt][nt][0] * i0r);
            oT[base +   C  ] = f2bf(oacc[mt][nt][1] * i1r);
            oT[base + 2*C  ] = f2bf(oacc[mt][nt][2] * i2r);
            oT[base + 3*C  ] = f2bf(oacc[mt][nt][3] * i3r);
        }
    }
}

// ---------------- Kernel 4: output projection + bias + residual ----------------
__global__ __launch_bounds__(256) void proj_kernel(
        const u16* __restrict__ oT, const float* __restrict__ wo,
        const float* __restrict__ bo, const float* __restrict__ x,
        float* __restrict__ out) {
    const int b = blockIdx.z, o0 = blockIdx.y * 64, i0 = blockIdx.x * 64;
    const int tid = threadIdx.x;
    const int tx = tid & 15, ty = tid >> 4;
    __shared__ float wS[16][65];
    __shared__ float oS[16][65];
    float acc[4][4];
    #pragma unroll
    for (int a = 0; a < 4; a++)
        #pragma unroll
        for (int bb = 0; bb < 4; bb++) acc[a][bb] = 0.f;
    for (int c0 = 0; c0 < C; c0 += 16) {
        __syncthreads();
        {
            int row = tid >> 2, col = (tid & 3) * 4;
            float4 w4 = *(const float4*)(wo + (size_t)(o0 + row) * C + c0 + col);
            wS[col+0][row] = w4.x; wS[col+1][row] = w4.y;
            wS[col+2][row] = w4.z; wS[col+3][row] = w4.w;
            int r = tid >> 2, cc = (tid & 3) * 4;
            ushort4 u4 = *(const ushort4*)(oT + ((size_t)b*HW + i0 + r)*C + c0 + cc);
            oS[cc+0][r] = bf2f(u4.x); oS[cc+1][r] = bf2f(u4.y);
            oS[cc+2][r] = bf2f(u4.z); oS[cc+3][r] = bf2f(u4.w);
        }
        __syncthreads();
        #pragma unroll
        for (int kk = 0; kk < 16; kk++) {
            float ov[4], wv_[4];
            #pragma unroll
            for (int bb = 0; bb < 4; bb++) ov[bb] = oS[kk][tx*4 + bb];
            #pragma unroll
            for (int a = 0; a < 4; a++) wv_[a] = wS[kk][ty*4 + a];
            #pragma unroll
            for (int a = 0; a < 4; a++)
                #pragma unroll
                for (int bb = 0; bb < 4; bb++)
                    acc[a][bb] += wv_[a] * ov[bb];
        }
    }
    #pragma unroll
    for (int a = 0; a < 4; a++) {
        int o = o0 + ty*4 + a;
        float bias = bo[o];
        size_t idx = ((size_t)b*C + o)*HW + i0 + tx*4;
        float4 xr = *(const float4*)(x + idx);
        float4 r;
        r.x = acc[a][0] + bias + xr.x;
        r.y = acc[a][1] + bias + xr.y;
        r.z = acc[a][2] + bias + xr.z;
        r.w = acc[a][3] + bias + xr.w;
        *(float4*)(out + idx) = r;
    }
}

extern "C" void kernel_launch(void* const* d_in, const int* in_sizes, int n_in,
                              void* d_out, int out_size, void* d_ws, size_t ws_size,
                              hipStream_t stream) {
    const float* x    = (const float*)d_in[0];
    const float* gn_w = (const float*)d_in[1];
    const float* gn_b = (const float*)d_in[2];
    const float* wq   = (const float*)d_in[3];
    const float* bq   = (const float*)d_in[4];
    const float* wk   = (const float*)d_in[5];
    const float* bk   = (const float*)d_in[6];
    const float* wv   = (const float*)d_in[7];
    const float* bv   = (const float*)d_in[8];
    const float* wo   = (const float*)d_in[9];
    const float* bo   = (const float*)d_in[10];
    float* out = (float*)d_out;

    const size_t S1 = (size_t)B * C * HW;   // 8,388,608 elements
    u16* xn   = (u16*)d_ws;
    u16* qT   = xn + S1;
    u16* kT   = qT + S1;
    u16* vimg = kT + S1;    // 4*128 chunks * 16384 u16 == S1
    u16* oT   = vimg + S1;

    hipLaunchKernelGGL(gn_kernel,  dim3(B*NG), dim3(256), 0, stream, x, gn_w, gn_b, xn);
    hipLaunchKernelGGL(qkv_kernel, dim3(HW/64, C/64, B), dim3(256), 0, stream,
                       xn, wq, bq, wk, bk, wv, bv, qT, kT, vimg);
    hipLaunchKernelGGL(attn_kernel, dim3(HW/64, B), dim3(256), 0, stream, qT, kT, vimg, oT);
    hipLaunchKernelGGL(proj_kernel, dim3(HW/64, C/64, B), dim3(256), 0, stream, oT, wo, bo, x, out);
}

// Round 3
// 605.894 us; speedup vs baseline: 8.6292x; 1.7651x over previous
//
#include <hip/hip_runtime.h>

#define B 4
#define C 512
#define HW 4096
#define NG 32
#define GSZ 65536   // (C/NG)*HW = 16*4096

typedef unsigned short u16;
typedef unsigned int u32;
typedef __attribute__((ext_vector_type(8))) short short8;
typedef __attribute__((ext_vector_type(4))) float f32x4;

__device__ __forceinline__ float bf2f(u16 u) {
    union { u32 i; float f; } x; x.i = ((u32)u) << 16; return x.f;
}
__device__ __forceinline__ u16 f2bf(float f) {
    union { u32 i; float f; } x; x.f = f;
    u32 r = x.i + 0x7FFF + ((x.i >> 16) & 1);   // round-nearest-even
    return (u16)(r >> 16);
}

// async global->LDS, 16B per lane. LDS dest = wave-uniform base + lane*16.
__device__ __forceinline__ void gld16(const u16* g, u16* l) {
    __builtin_amdgcn_global_load_lds(
        (const __attribute__((address_space(1))) void*)g,
        (__attribute__((address_space(3))) void*)l, 16, 0, 0);
}

// ---------------- Kernel 0: fp32 -> bf16 weight conversion ----------------
__global__ __launch_bounds__(256) void conv_kernel(
        const float* __restrict__ wq, const float* __restrict__ wk,
        const float* __restrict__ wv, const float* __restrict__ wo,
        u16* __restrict__ dst) {
    const int mat = blockIdx.y;
    const float* src = (mat == 0) ? wq : (mat == 1) ? wk : (mat == 2) ? wv : wo;
    const int idx = (blockIdx.x * 256 + threadIdx.x) * 4;   // grid.x=256 -> 262144
    float4 v = *(const float4*)(src + idx);
    ushort4 r;
    r.x = f2bf(v.x); r.y = f2bf(v.y); r.z = f2bf(v.z); r.w = f2bf(v.w);
    *(ushort4*)(dst + (size_t)mat * (C * C) + idx) = r;
}

// ---------------- Kernel 1: GroupNorm -> bf16 xnT (b, hw, c) ----------------
__global__ __launch_bounds__(256) void gn_kernel(
        const float* __restrict__ x, const float* __restrict__ gamma,
        const float* __restrict__ beta, u16* __restrict__ xnT) {
    const int gl = blockIdx.x;                // b*32 + g
    const int b = gl >> 5, g = gl & 31;
    const size_t base = (size_t)gl * GSZ;
    const int tid = threadIdx.x;
    float s = 0.f, s2 = 0.f;
    for (int i = tid * 4; i < GSZ; i += 1024) {
        float4 v4 = *(const float4*)(x + base + i);
        s  += v4.x + v4.y + v4.z + v4.w;
        s2 += v4.x*v4.x + v4.y*v4.y + v4.z*v4.z + v4.w*v4.w;
    }
    #pragma unroll
    for (int off = 32; off > 0; off >>= 1) {
        s  += __shfl_down(s, off, 64);
        s2 += __shfl_down(s2, off, 64);
    }
    __shared__ float rs[4], rs2[4], bc[2];
    int lane = tid & 63, wid = tid >> 6;
    if (lane == 0) { rs[wid] = s; rs2[wid] = s2; }
    __syncthreads();
    if (tid == 0) {
        float ts  = rs[0] + rs[1] + rs[2] + rs[3];
        float ts2 = rs2[0] + rs2[1] + rs2[2] + rs2[3];
        float mean = ts * (1.f / GSZ);
        float var  = ts2 * (1.f / GSZ) - mean * mean;
        bc[0] = mean; bc[1] = rsqrtf(var + 1e-6f);
    }
    __syncthreads();
    const float mean = bc[0], rstd = bc[1];
    const int c0 = g * 16;
    float gm[16], bt[16];
    #pragma unroll
    for (int c = 0; c < 16; c++) {
        float gg = gamma[c0 + c] * rstd;
        gm[c] = gg;
        bt[c] = beta[c0 + c] - mean * gg;
    }
    for (int i = tid; i < HW; i += 256) {
        u32 pk[8];
        #pragma unroll
        for (int c = 0; c < 16; c += 2) {
            float a0 = x[base + (size_t)c * HW + i] * gm[c] + bt[c];
            float a1 = x[base + (size_t)(c + 1) * HW + i] * gm[c + 1] + bt[c + 1];
            pk[c >> 1] = (u32)f2bf(a0) | ((u32)f2bf(a1) << 16);
        }
        u16* dst = xnT + ((size_t)b * HW + i) * C + c0;
        *(uint4*)dst       = make_uint4(pk[0], pk[1], pk[2], pk[3]);
        *(uint4*)(dst + 8) = make_uint4(pk[4], pk[5], pk[6], pk[7]);
    }
}

// ---------------- Kernel 2: MFMA QKV projection ----------------
// A = xnT (m=i, k=c contig), B = W (n=o, k=c contig) -> D[i,o]
// q/k: store qT/kT (b,hw,c);  v: store vimg swizzled chunks (ushort4 runs)
__global__ __launch_bounds__(256) void qkv_kernel(
        const u16* __restrict__ xnT, const u16* __restrict__ wb,
        const float* __restrict__ bq, const float* __restrict__ bk,
        const float* __restrict__ bv,
        u16* __restrict__ qT, u16* __restrict__ kT, u16* __restrict__ vimg) {
    const int mat = blockIdx.y >> 2;
    const int oT0 = (blockIdx.y & 3) * 128;
    const int iT0 = blockIdx.x * 128;
    const int b = blockIdx.z;
    const u16* Ag = xnT + ((size_t)b * HW + iT0) * C;
    const u16* Bg = wb + (size_t)mat * C * C + (size_t)oT0 * C;
    const float* bias = (mat == 0) ? bq : (mat == 1) ? bk : bv;

    const int tid = threadIdx.x;
    const int w = tid >> 6, lane = tid & 63;
    const int qd = lane >> 4, nn = lane & 15;
    const int wm = w & 1, wn = w >> 1;

    __shared__ __align__(16) u16 As[2][128 * 32];
    __shared__ __align__(16) u16 Bs[2][128 * 32];

    f32x4 acc[4][4];
    #pragma unroll
    for (int mt = 0; mt < 4; mt++)
        #pragma unroll
        for (int nt = 0; nt < 4; nt++) acc[mt][nt] = (f32x4){0.f, 0.f, 0.f, 0.f};

    auto stage = [&](u16* dst, const u16* g, int c0) {
        #pragma unroll
        for (int p = 0; p < 2; p++) {
            int rbase = 32 * w + 16 * p;
            int row = rbase + (lane >> 2);
            gld16(g + (size_t)row * C + c0 + (((lane & 3) ^ ((row >> 1) & 3)) << 3),
                  dst + rbase * 32);
        }
    };

    stage(As[0], Ag, 0);
    stage(Bs[0], Bg, 0);

    for (int kt = 0; kt < 16; kt++) {
        const int cur = kt & 1;
        __syncthreads();
        if (kt < 15) {
            stage(As[cur ^ 1], Ag, (kt + 1) * 32);
            stage(Bs[cur ^ 1], Bg, (kt + 1) * 32);
        }
        short8 af[4], bf[4];
        #pragma unroll
        for (int mt = 0; mt < 4; mt++) {
            int row = 64 * wm + 16 * mt + nn;
            af[mt] = *(const short8*)&As[cur][row * 32 + ((qd ^ ((row >> 1) & 3)) << 3)];
        }
        #pragma unroll
        for (int nt = 0; nt < 4; nt++) {
            int row = 64 * wn + 16 * nt + nn;
            bf[nt] = *(const short8*)&Bs[cur][row * 32 + ((qd ^ ((row >> 1) & 3)) << 3)];
        }
        #pragma unroll
        for (int mt = 0; mt < 4; mt++)
            #pragma unroll
            for (int nt = 0; nt < 4; nt++)
                acc[mt][nt] = __builtin_amdgcn_mfma_f32_16x16x32_bf16(af[mt], bf[nt], acc[mt][nt], 0, 0, 0);
    }

    if (mat < 2) {
        u16* dstT = ((mat == 0) ? qT : kT) + (size_t)b * HW * C;
        #pragma unroll
        for (int nt = 0; nt < 4; nt++) {
            int o = oT0 + 64 * wn + 16 * nt + nn;
            float bb = bias[o];
            #pragma unroll
            for (int mt = 0; mt < 4; mt++) {
                int ib = iT0 + 64 * wm + 16 * mt + qd * 4;
                u16* p = dstT + (size_t)ib * C + o;
                p[0]     = f2bf(acc[mt][nt][0] + bb);
                p[C]     = f2bf(acc[mt][nt][1] + bb);
                p[2 * C] = f2bf(acc[mt][nt][2] + bb);
                p[3 * C] = f2bf(acc[mt][nt][3] + bb);
            }
        }
    } else {
        u16* vb = vimg + (size_t)b * 128 * 16384;
        #pragma unroll
        for (int nt = 0; nt < 4; nt++) {
            int c = oT0 + 64 * wn + 16 * nt + nn;
            float bb = bias[c];
            #pragma unroll
            for (int mt = 0; mt < 4; mt++) {
                int ib = iT0 + 64 * wm + 16 * mt + qd * 4;
                int ch = ib >> 5;
                int j0 = ib & 31;
                ushort4 st;
                st.x = f2bf(acc[mt][nt][0] + bb);
                st.y = f2bf(acc[mt][nt][1] + bb);
                st.z = f2bf(acc[mt][nt][2] + bb);
                st.w = f2bf(acc[mt][nt][3] + bb);
                *(ushort4*)&vb[(size_t)ch * 16384 + c * 32 +
                               (((j0 >> 3) ^ ((c >> 2) & 3)) << 3) + (j0 & 7)] = st;
            }
        }
    }
}

// ---------------- Kernel 3: MFMA flash attention ----------------
__global__ __launch_bounds__(256) void attn_kernel(
        const u16* __restrict__ qT, const u16* __restrict__ kT,
        const u16* __restrict__ vimg, u16* __restrict__ oT) {
    const int b = blockIdx.y;
    const int i0 = blockIdx.x * 64;
    const int tid = threadIdx.x;
    const int w = tid >> 6;
    const int lane = tid & 63;
    const int q = lane >> 4;
    const int n = lane & 15;

    __shared__ __align__(16) u16 kbuf[2][32*520];
    __shared__ __align__(16) u16 vbuf[2][16384];
    __shared__ __align__(16) u16 pbuf[64*40];
    __shared__ __align__(16) float alphabuf[64];
    __shared__ __align__(16) float lbuf[64];
    __shared__ int flagbuf[4];

    short8 qf[16];
    {
        const u16* qrow = qT + ((size_t)b*HW + i0 + w*16 + n) * C + q*8;
        #pragma unroll
        for (int k = 0; k < 16; k++) {
            uint4 u = *(const uint4*)(qrow + k*32);
            qf[k] = *(const short8*)&u;
        }
    }
    f32x4 oacc[4][8];
    #pragma unroll
    for (int mt = 0; mt < 4; mt++)
        #pragma unroll
        for (int nt = 0; nt < 8; nt++)
            oacc[mt][nt] = (f32x4){0.f, 0.f, 0.f, 0.f};
    float mstate[4] = {-1e30f, -1e30f, -1e30f, -1e30f};
    float lsum[4]   = {0.f, 0.f, 0.f, 0.f};

    const u16* kTb = kT + (size_t)b*HW*C;
    const u16* vTb = vimg + (size_t)b*128*16384;

    {
        #pragma unroll
        for (int ii = 0; ii < 8; ii++) {
            int row = w*8 + ii;
            gld16(kTb + (size_t)row*C + lane*8, &kbuf[0][row*520]);
        }
        #pragma unroll
        for (int ii = 0; ii < 8; ii++) {
            int t = w*8 + ii;
            gld16(vTb + t*512 + lane*8, &vbuf[0][t*512]);
        }
    }
    const float scale = 0.04419417382415922f;

    for (int t = 0; t < 128; ++t) {
        const int cur = t & 1;
        __syncthreads();
        if (t + 1 < 128) {
            const u16* gk = kTb + (size_t)(t+1)*32*C;
            #pragma unroll
            for (int ii = 0; ii < 8; ii++) {
                int row = w*8 + ii;
                gld16(gk + (size_t)row*C + lane*8, &kbuf[cur^1][row*520]);
            }
        }
        f32x4 s0 = {0.f,0.f,0.f,0.f}, s1 = {0.f,0.f,0.f,0.f};
        const u16* kb = kbuf[cur];
        const u16* kb0 = kb + n*520 + q*8;
        const u16* kb1 = kb + (16+n)*520 + q*8;
        #pragma unroll
        for (int k = 0; k < 16; k++) {
            short8 bf = *(const short8*)(kb0 + k*32);
            s0 = __builtin_amdgcn_mfma_f32_16x16x32_bf16(qf[k], bf, s0, 0, 0, 0);
        }
        #pragma unroll
        for (int k = 0; k < 16; k++) {
            short8 bf = *(const short8*)(kb1 + k*32);
            s1 = __builtin_amdgcn_mfma_f32_16x16x32_bf16(qf[k], bf, s1, 0, 0, 0);
        }
        float alr[4];
        #pragma unroll
        for (int r = 0; r < 4; r++) {
            float v0 = s0[r]*scale, v1 = s1[r]*scale;
            float mx = fmaxf(v0, v1);
            mx = fmaxf(mx, __shfl_xor(mx, 1));
            mx = fmaxf(mx, __shfl_xor(mx, 2));
            mx = fmaxf(mx, __shfl_xor(mx, 4));
            mx = fmaxf(mx, __shfl_xor(mx, 8));
            float mnew = fmaxf(mstate[r], mx);
            float al = __expf(mstate[r] - mnew);
            float p0 = __expf(v0 - mnew);
            float p1 = __expf(v1 - mnew);
            mstate[r] = mnew;
            lsum[r] = lsum[r]*al + (p0 + p1);
            alr[r] = al;
            pbuf[(w*16 + q*4 + r)*40 + n]      = f2bf(p0);
            pbuf[(w*16 + q*4 + r)*40 + 16 + n] = f2bf(p1);
        }
        int chg = (alr[0]!=1.f) | (alr[1]!=1.f) | (alr[2]!=1.f) | (alr[3]!=1.f);
        int anyc = __any(chg);
        if (lane == 0) flagbuf[w] = anyc;
        if (n == 0) {
            #pragma unroll
            for (int r = 0; r < 4; r++) alphabuf[w*16 + q*4 + r] = alr[r];
        }
        __syncthreads();
        if (t + 1 < 128) {
            const u16* gv = vTb + (size_t)(t+1)*16384;
            #pragma unroll
            for (int ii = 0; ii < 8; ii++) {
                int tt = w*8 + ii;
                gld16(gv + tt*512 + lane*8, &vbuf[cur^1][tt*512]);
            }
        }
        int doR = flagbuf[0] | flagbuf[1] | flagbuf[2] | flagbuf[3];
        if (doR) {
            #pragma unroll
            for (int mt = 0; mt < 4; mt++) {
                f32x4 a4 = *(const f32x4*)&alphabuf[mt*16 + q*4];
                #pragma unroll
                for (int nt = 0; nt < 8; nt++) {
                    oacc[mt][nt][0] *= a4[0];
                    oacc[mt][nt][1] *= a4[1];
                    oacc[mt][nt][2] *= a4[2];
                    oacc[mt][nt][3] *= a4[3];
                }
            }
        }
        short8 pf[4];
        #pragma unroll
        for (int mt = 0; mt < 4; mt++)
            pf[mt] = *(const short8*)&pbuf[(mt*16 + n)*40 + q*8];
        const u16* vb = vbuf[cur];
        #pragma unroll
        for (int nt = 0; nt < 8; nt++) {
            int c = w*128 + nt*16 + n;
            short8 vf = *(const short8*)&vb[c*32 + ((q ^ ((c>>2)&3)) << 3)];
            #pragma unroll
            for (int mt = 0; mt < 4; mt++)
                oacc[mt][nt] = __builtin_amdgcn_mfma_f32_16x16x32_bf16(pf[mt], vf, oacc[mt][nt], 0, 0, 0);
        }
    }
    #pragma unroll
    for (int r = 0; r < 4; r++) {
        float l = lsum[r];
        l += __shfl_xor(l, 1);
        l += __shfl_xor(l, 2);
        l += __shfl_xor(l, 4);
        l += __shfl_xor(l, 8);
        if (n == 0) lbuf[w*16 + q*4 + r] = l;
    }
    __syncthreads();
    #pragma unroll
    for (int mt = 0; mt < 4; mt++) {
        f32x4 l4 = *(const f32x4*)&lbuf[mt*16 + q*4];
        float i0r = 1.f / l4[0], i1r = 1.f / l4[1], i2r = 1.f / l4[2], i3r = 1.f / l4[3];
        #pragma unroll
        for (int nt = 0; nt < 8; nt++) {
            int cc = w*128 + nt*16 + n;
            size_t base = ((size_t)b*HW + i0 + mt*16 + q*4) * C + cc;
            oT[base        ] = f2bf(oacc[mt][nt][0] * i0r);
            oT[base +   C  ] = f2bf(oacc[mt][nt][1] * i1r);
            oT[base + 2*C  ] = f2bf(oacc[mt][nt][2] * i2r);
            oT[base + 3*C  ] = f2bf(oacc[mt][nt][3] * i3r);
        }
    }
}

// ---------------- Kernel 4: MFMA output projection + bias + residual ----------------
// A = wo (m=o, k=c), B = oT (n=i, k=c) -> D[o,i] (c-major output)
__global__ __launch_bounds__(256) void proj_kernel(
        const u16* __restrict__ oT, const u16* __restrict__ wob,
        const float* __restrict__ bo, const float* __restrict__ x,
        float* __restrict__ out) {
    const int o0 = blockIdx.y * 128;
    const int i0t = blockIdx.x * 128;
    const int b = blockIdx.z;
    const u16* Ag = wob + (size_t)o0 * C;
    const u16* Bg = oT + ((size_t)b * HW + i0t) * C;

    const int tid = threadIdx.x;
    const int w = tid >> 6, lane = tid & 63;
    const int qd = lane >> 4, nn = lane & 15;
    const int wm = w & 1, wn = w >> 1;

    __shared__ __align__(16) u16 As[2][128 * 32];
    __shared__ __align__(16) u16 Bs[2][128 * 32];

    f32x4 acc[4][4];
    #pragma unroll
    for (int mt = 0; mt < 4; mt++)
        #pragma unroll
        for (int nt = 0; nt < 4; nt++) acc[mt][nt] = (f32x4){0.f, 0.f, 0.f, 0.f};

    auto stage = [&](u16* dst, const u16* g, int c0) {
        #pragma unroll
        for (int p = 0; p < 2; p++) {
            int rbase = 32 * w + 16 * p;
            int row = rbase + (lane >> 2);
            gld16(g + (size_t)row * C + c0 + (((lane & 3) ^ ((row >> 1) & 3)) << 3),
                  dst + rbase * 32);
        }
    };

    stage(As[0], Ag, 0);
    stage(Bs[0], Bg, 0);

    for (int kt = 0; kt < 16; kt++) {
        const int cur = kt & 1;
        __syncthreads();
        if (kt < 15) {
            stage(As[cur ^ 1], Ag, (kt + 1) * 32);
            stage(Bs[cur ^ 1], Bg, (kt + 1) * 32);
        }
        short8 af[4], bf[4];
        #pragma unroll
        for (int mt = 0; mt < 4; mt++) {
            int row = 64 * wm + 16 * mt + nn;
            af[mt] = *(const short8*)&As[cur][row * 32 + ((qd ^ ((row >> 1) & 3)) << 3)];
        }
        #pragma unroll
        for (int nt = 0; nt < 4; nt++) {
            int row = 64 * wn + 16 * nt + nn;
            bf[nt] = *(const short8*)&Bs[cur][row * 32 + ((qd ^ ((row >> 1) & 3)) << 3)];
        }
        #pragma unroll
        for (int mt = 0; mt < 4; mt++)
            #pragma unroll
            for (int nt = 0; nt < 4; nt++)
                acc[mt][nt] = __builtin_amdgcn_mfma_f32_16x16x32_bf16(af[mt], bf[nt], acc[mt][nt], 0, 0, 0);
    }

    #pragma unroll
    for (int mt = 0; mt < 4; mt++) {
        #pragma unroll
        for (int r = 0; r < 4; r++) {
            int o = o0 + 64 * wm + 16 * mt + qd * 4 + r;
            float bb = bo[o];
            #pragma unroll
            for (int nt = 0; nt < 4; nt++) {
                int i = i0t + 64 * wn + 16 * nt + nn;
                size_t idx = ((size_t)b * C + o) * HW + i;
                out[idx] = acc[mt][nt][r] + bb + x[idx];
            }
        }
    }
}

extern "C" void kernel_launch(void* const* d_in, const int* in_sizes, int n_in,
                              void* d_out, int out_size, void* d_ws, size_t ws_size,
                              hipStream_t stream) {
    const float* x    = (const float*)d_in[0];
    const float* gn_w = (const float*)d_in[1];
    const float* gn_b = (const float*)d_in[2];
    const float* wq   = (const float*)d_in[3];
    const float* bq   = (const float*)d_in[4];
    const float* wk   = (const float*)d_in[5];
    const float* bk   = (const float*)d_in[6];
    const float* wv   = (const float*)d_in[7];
    const float* bv   = (const float*)d_in[8];
    const float* wo   = (const float*)d_in[9];
    const float* bo   = (const float*)d_in[10];
    float* out = (float*)d_out;

    const size_t WSZ = (size_t)C * C;        // 262144
    const size_t S1  = (size_t)B * C * HW;   // 8,388,608
    u16* wb   = (u16*)d_ws;                  // [q,k,v,o] bf16 weights
    u16* wob  = wb + 3 * WSZ;
    u16* xnT  = wob + WSZ;
    u16* qT   = xnT + S1;
    u16* kT   = qT + S1;
    u16* vimg = kT + S1;
    u16* oT   = vimg + S1;

    hipLaunchKernelGGL(conv_kernel, dim3(256, 4), dim3(256), 0, stream, wq, wk, wv, wo, wb);
    hipLaunchKernelGGL(gn_kernel,   dim3(B*NG), dim3(256), 0, stream, x, gn_w, gn_b, xnT);
    hipLaunchKernelGGL(qkv_kernel,  dim3(HW/128, 12, B), dim3(256), 0, stream,
                       xnT, wb, bq, bk, bv, qT, kT, vimg);
    hipLaunchKernelGGL(attn_kernel, dim3(HW/64, B), dim3(256), 0, stream, qT, kT, vimg, oT);
    hipLaunchKernelGGL(proj_kernel, dim3(HW/128, C/128, B), dim3(256), 0, stream, oT, wob, bo, x, out);
}